// Round 1
// baseline (3344.074 us; speedup 1.0000x reference)
//
#include <hip/hip_runtime.h>

#define NN 50000
#define NE 800000
#define EP (NE + NN)      // edges + self loops = 850000
#define NG 128
#define F 128

// C[N,128] = A[N,128] @ W[128,128], fp32. 2 rows per block, 256 threads.
__global__ void gemm128(const float* __restrict__ A, const float* __restrict__ W,
                        float* __restrict__ C, int N) {
    __shared__ float xs[256];
    const int tid = threadIdx.x;
    const int r = tid >> 7, c = tid & 127;
    const int row = blockIdx.x * 2 + r;
    if (row < N) xs[tid] = A[row * F + c];
    __syncthreads();
    if (row >= N) return;
    const float* xr = xs + r * F;
    float acc = 0.f;
#pragma unroll 8
    for (int k = 0; k < F; ++k) acc = fmaf(xr[k], W[k * F + c], acc);
    C[row * F + c] = acc;
}

// per-node attention scores: asrc[n] = h[n,:]@att_src, adst[n] = h[n,:]@att_dst
// one wave (64 lanes) per node, 4 nodes per 256-thread block
__global__ void node_scores(const float* __restrict__ h, const float* __restrict__ as,
                            const float* __restrict__ ad, float* __restrict__ asrc,
                            float* __restrict__ adst, int N) {
    const int node = blockIdx.x * 4 + (threadIdx.x >> 6);
    const int lane = threadIdx.x & 63;
    if (node >= N) return;
    const float* hr = h + node * F;
    float v1 = hr[lane] * as[lane] + hr[lane + 64] * as[lane + 64];
    float v2 = hr[lane] * ad[lane] + hr[lane + 64] * ad[lane + 64];
    for (int o = 32; o; o >>= 1) { v1 += __shfl_xor(v1, o); v2 += __shfl_xor(v2, o); }
    if (lane == 0) { asrc[node] = v1; adst[node] = v2; }
}

// per-edge: ex = exp(leaky_relu(asrc[s]+adst[d])); denom[d] += ex; deg[d] += 1
// (segment_max skipped: scores are O(1), exp is safe in fp32; alpha identical)
__global__ void edge_scores(const int* __restrict__ ei, const float* __restrict__ asrc,
                            const float* __restrict__ adst, float* __restrict__ exb,
                            float* __restrict__ denom, float* __restrict__ deg) {
    const int e = blockIdx.x * blockDim.x + threadIdx.x;
    if (e >= EP) return;
    int s, d;
    if (e < NE) { s = ei[e]; d = ei[NE + e]; } else { s = d = e - NE; }
    float sc = asrc[s] + adst[d];
    sc = sc > 0.f ? sc : 0.2f * sc;
    const float ex = expf(sc);
    exb[e] = ex;
    atomicAdd(denom + d, ex);
    atomicAdd(deg + d, 1.0f);
}

// GAT aggregation: acc[d,:] += (ex[e]/denom[d]) * h[s,:]  -- 32 threads/edge, float4
__global__ void gat_agg(const int* __restrict__ ei, const float* __restrict__ exb,
                        const float* __restrict__ denom, const float* __restrict__ h,
                        float* __restrict__ acc) {
    const int idx = blockIdx.x * blockDim.x + threadIdx.x;
    const int e = idx >> 5;
    if (e >= EP) return;
    const int q = (idx & 31) << 2;
    int s, d;
    if (e < NE) { s = ei[e]; d = ei[NE + e]; } else { s = d = e - NE; }
    const float w = exb[e] / denom[d];
    const float4 hv = *(const float4*)(h + s * F + q);
    float* o = acc + d * F + q;
    atomicAdd(o + 0, w * hv.x);
    atomicAdd(o + 1, w * hv.y);
    atomicAdd(o + 2, w * hv.z);
    atomicAdd(o + 3, w * hv.w);
}

// GCN aggregation: acc[d,:] += rsqrt(deg[s])*rsqrt(deg[d]) * h[s,:]
__global__ void gcn_agg(const int* __restrict__ ei, const float* __restrict__ deg,
                        const float* __restrict__ h, float* __restrict__ acc) {
    const int idx = blockIdx.x * blockDim.x + threadIdx.x;
    const int e = idx >> 5;
    if (e >= EP) return;
    const int q = (idx & 31) << 2;
    int s, d;
    if (e < NE) { s = ei[e]; d = ei[NE + e]; } else { s = d = e - NE; }
    const float w = rsqrtf(deg[s]) * rsqrtf(deg[d]);   // deg >= 1 (self loops)
    const float4 hv = *(const float4*)(h + s * F + q);
    float* o = acc + d * F + q;
    atomicAdd(o + 0, w * hv.x);
    atomicAdd(o + 1, w * hv.y);
    atomicAdd(o + 2, w * hv.z);
    atomicAdd(o + 3, w * hv.w);
}

__global__ void bias_relu(float* __restrict__ a, const float* __restrict__ b, int total) {
    const int i = blockIdx.x * blockDim.x + threadIdx.x;
    if (i >= total) return;
    const float v = a[i] + b[i & (F - 1)];
    a[i] = v > 0.f ? v : 0.f;
}

// mean-pool per graph (batch sorted) + final linear [128 -> 2]
__global__ void pool_head(const float* __restrict__ h, const int* __restrict__ batch,
                          const float* __restrict__ Wf, const float* __restrict__ bf,
                          float* __restrict__ out, int N) {
    const int g = blockIdx.x;
    const int f = threadIdx.x;  // 128 threads
    // lower_bound(batch, g) and lower_bound(batch, g+1)
    int lo = 0, hi = N;
    while (lo < hi) { int m = (lo + hi) >> 1; if (batch[m] < g) lo = m + 1; else hi = m; }
    int lo2 = lo, hi2 = N;
    while (lo2 < hi2) { int m = (lo2 + hi2) >> 1; if (batch[m] < g + 1) lo2 = m + 1; else hi2 = m; }
    float s = 0.f;
    for (int n = lo; n < lo2; ++n) s += h[n * F + f];
    const float cnt = (float)(lo2 - lo);
    const float rep = s / fmaxf(cnt, 1.0f);
    float p0 = rep * Wf[f * 2 + 0];
    float p1 = rep * Wf[f * 2 + 1];
    for (int o = 32; o; o >>= 1) { p0 += __shfl_xor(p0, o); p1 += __shfl_xor(p1, o); }
    __shared__ float r0[2], r1[2];
    if ((threadIdx.x & 63) == 0) { r0[threadIdx.x >> 6] = p0; r1[threadIdx.x >> 6] = p1; }
    __syncthreads();
    if (threadIdx.x == 0) out[g * 2 + 0] = r0[0] + r0[1] + bf[0];
    if (threadIdx.x == 1) out[g * 2 + 1] = r1[0] + r1[1] + bf[1];
}

extern "C" void kernel_launch(void* const* d_in, const int* in_sizes, int n_in,
                              void* d_out, int out_size, void* d_ws, size_t ws_size,
                              hipStream_t stream) {
    const float* x       = (const float*)d_in[0];
    const float* W1      = (const float*)d_in[1];
    const float* att_src = (const float*)d_in[2];
    const float* att_dst = (const float*)d_in[3];
    const float* b1      = (const float*)d_in[4];
    const float* W2      = (const float*)d_in[5];
    const float* b2      = (const float*)d_in[6];
    const float* Wf      = (const float*)d_in[7];
    const float* bf      = (const float*)d_in[8];
    const int*   ei      = (const int*)d_in[9];
    const int*   batch   = (const int*)d_in[10];
    float* out = (float*)d_out;

    // workspace layout (floats); total 20.25M floats = 81 MB
    float* ws    = (float*)d_ws;
    float* h1    = ws;                  // 6.4M
    float* asrc  = h1 + (size_t)NN * F; // 50k
    float* adst  = asrc + NN;           // 50k
    float* denom = adst + NN;           // 50k
    float* deg   = denom + NN;          // 50k
    float* exb   = deg + NN;            // 850k
    float* acc1  = exb + EP;            // 6.4M  (becomes relu(h1_agg) in place)
    float* h2    = acc1 + (size_t)NN * F; // 6.4M
    float* acc2  = h1;                  // alias: h1 dead after gat_agg

    const int TOT = NN * F;             // 6.4M

    hipMemsetAsync(denom, 0, (size_t)2 * NN * sizeof(float), stream); // denom+deg contiguous
    hipMemsetAsync(acc1, 0, (size_t)TOT * sizeof(float), stream);

    gemm128<<<NN / 2, 256, 0, stream>>>(x, W1, h1, NN);
    node_scores<<<(NN + 3) / 4, 256, 0, stream>>>(h1, att_src, att_dst, asrc, adst, NN);
    edge_scores<<<(EP + 255) / 256, 256, 0, stream>>>(ei, asrc, adst, exb, denom, deg);
    gat_agg<<<(EP * 32 + 255) / 256, 256, 0, stream>>>(ei, exb, denom, h1, acc1);
    bias_relu<<<(TOT + 255) / 256, 256, 0, stream>>>(acc1, b1, TOT);
    gemm128<<<NN / 2, 256, 0, stream>>>(acc1, W2, h2, NN);
    hipMemsetAsync(acc2, 0, (size_t)TOT * sizeof(float), stream);  // after h1 is dead
    gcn_agg<<<(EP * 32 + 255) / 256, 256, 0, stream>>>(ei, deg, h2, acc2);
    bias_relu<<<(TOT + 255) / 256, 256, 0, stream>>>(acc2, b2, TOT);
    pool_head<<<NG, 128, 0, stream>>>(acc2, batch, Wf, bf, out, NN);
}

// Round 2
// 742.035 us; speedup vs baseline: 4.5066x; 4.5066x over previous
//
#include <hip/hip_runtime.h>

#define NN 50000
#define NE 800000
#define EP (NE + NN)      // edges + self loops = 850000
#define NG 128
#define F 128

// C[N,128] = A[N,128] @ W[128,128], fp32. 2 rows per block, 256 threads.
__global__ void gemm128(const float* __restrict__ A, const float* __restrict__ W,
                        float* __restrict__ C, int N) {
    __shared__ float xs[256];
    const int tid = threadIdx.x;
    const int r = tid >> 7, c = tid & 127;
    const int row = blockIdx.x * 2 + r;
    if (row < N) xs[tid] = A[row * F + c];
    __syncthreads();
    if (row >= N) return;
    const float* xr = xs + r * F;
    float acc = 0.f;
#pragma unroll 8
    for (int k = 0; k < F; ++k) acc = fmaf(xr[k], W[k * F + c], acc);
    C[row * F + c] = acc;
}

// per-node attention scores: asrc[n] = h[n,:]@att_src, adst[n] = h[n,:]@att_dst
__global__ void node_scores(const float* __restrict__ h, const float* __restrict__ as,
                            const float* __restrict__ ad, float* __restrict__ asrc,
                            float* __restrict__ adst, int N) {
    const int node = blockIdx.x * 4 + (threadIdx.x >> 6);
    const int lane = threadIdx.x & 63;
    if (node >= N) return;
    const float* hr = h + node * F;
    float v1 = hr[lane] * as[lane] + hr[lane + 64] * as[lane + 64];
    float v2 = hr[lane] * ad[lane] + hr[lane + 64] * ad[lane + 64];
    for (int o = 32; o; o >>= 1) { v1 += __shfl_xor(v1, o); v2 += __shfl_xor(v2, o); }
    if (lane == 0) { asrc[node] = v1; adst[node] = v2; }
}

// ---- CSR build: histogram -> scan -> scatter ----
__global__ void hist_deg(const int* __restrict__ ei, int* __restrict__ deg) {
    const int e = blockIdx.x * blockDim.x + threadIdx.x;
    if (e >= EP) return;
    const int d = (e < NE) ? ei[NE + e] : e - NE;
    atomicAdd(deg + d, 1);
}

// exclusive scan of deg[NN] -> row_start[NN+1]; single block, 1024 threads
__global__ void scan_rows(const int* __restrict__ deg, int* __restrict__ row_start) {
    __shared__ int part[1024];
    const int t = threadIdx.x;
    const int CH = (NN + 1023) / 1024;  // 49
    const int lo = t * CH, hi = min(lo + CH, NN);
    int s = 0;
    for (int i = lo; i < hi; ++i) s += deg[i];
    part[t] = s;
    __syncthreads();
    for (int o = 1; o < 1024; o <<= 1) {
        int v = (t >= o) ? part[t - o] : 0;
        __syncthreads();
        part[t] += v;
        __syncthreads();
    }
    int run = part[t] - s;  // exclusive base for this chunk
    for (int i = lo; i < hi; ++i) { row_start[i] = run; run += deg[i]; }
    if (t == 1023) row_start[NN] = part[1023];
}

__global__ void scatter_csr(const int* __restrict__ ei, const int* __restrict__ row_start,
                            int* __restrict__ cnt, int* __restrict__ csr_src) {
    const int e = blockIdx.x * blockDim.x + threadIdx.x;
    if (e >= EP) return;
    int s, d;
    if (e < NE) { s = ei[e]; d = ei[NE + e]; } else { s = d = e - NE; }
    const int pos = row_start[d] + atomicAdd(cnt + d, 1);
    csr_src[pos] = s;
}

// ---- GAT gather: one wave per dst node; softmax denom + weighted sum fused ----
__global__ void gat_gather(const int* __restrict__ row_start, const int* __restrict__ csr_src,
                           const float* __restrict__ asrc, const float* __restrict__ adst,
                           const float* __restrict__ h, const float* __restrict__ bias,
                           float* __restrict__ out) {
    const int n = blockIdx.x * 4 + (threadIdx.x >> 6);
    const int lane = threadIdx.x & 63;
    if (n >= NN) return;
    const int lo = row_start[n], hi = row_start[n + 1];
    const float adn = adst[n];
    // pass 1: denom (lanes split over edges)
    float den = 0.f;
    for (int i = lo + lane; i < hi; i += 64) {
        float sc = asrc[csr_src[i]] + adn;
        sc = sc > 0.f ? sc : 0.2f * sc;
        den += expf(sc);
    }
    for (int o = 32; o; o >>= 1) den += __shfl_xor(den, o);
    const float inv = 1.f / den;
    // pass 2: lanes split over features (2 each), serial over edges
    float2 acc = {0.f, 0.f};
    for (int i = lo; i < hi; ++i) {
        const int s = csr_src[i];                 // wave-uniform broadcast load
        float sc = asrc[s] + adn;
        sc = sc > 0.f ? sc : 0.2f * sc;
        const float w = expf(sc) * inv;
        const float2 hv = *(const float2*)(h + (size_t)s * F + lane * 2);
        acc.x = fmaf(w, hv.x, acc.x);
        acc.y = fmaf(w, hv.y, acc.y);
    }
    const float v0 = acc.x + bias[lane * 2];
    const float v1 = acc.y + bias[lane * 2 + 1];
    float2* o = (float2*)(out + (size_t)n * F + lane * 2);
    *o = make_float2(v0 > 0.f ? v0 : 0.f, v1 > 0.f ? v1 : 0.f);
}

__global__ void make_dinv(const int* __restrict__ row_start, float* __restrict__ dinv) {
    const int n = blockIdx.x * blockDim.x + threadIdx.x;
    if (n >= NN) return;
    dinv[n] = rsqrtf((float)(row_start[n + 1] - row_start[n]));  // deg >= 1 (self loop)
}

// ---- GCN gather ----
__global__ void gcn_gather(const int* __restrict__ row_start, const int* __restrict__ csr_src,
                           const float* __restrict__ dinv, const float* __restrict__ h,
                           const float* __restrict__ bias, float* __restrict__ out) {
    const int n = blockIdx.x * 4 + (threadIdx.x >> 6);
    const int lane = threadIdx.x & 63;
    if (n >= NN) return;
    const int lo = row_start[n], hi = row_start[n + 1];
    const float dn = dinv[n];
    float2 acc = {0.f, 0.f};
    for (int i = lo; i < hi; ++i) {
        const int s = csr_src[i];
        const float w = dinv[s] * dn;
        const float2 hv = *(const float2*)(h + (size_t)s * F + lane * 2);
        acc.x = fmaf(w, hv.x, acc.x);
        acc.y = fmaf(w, hv.y, acc.y);
    }
    const float v0 = acc.x + bias[lane * 2];
    const float v1 = acc.y + bias[lane * 2 + 1];
    float2* o = (float2*)(out + (size_t)n * F + lane * 2);
    *o = make_float2(v0 > 0.f ? v0 : 0.f, v1 > 0.f ? v1 : 0.f);
}

// mean-pool per graph (batch sorted) + final linear [128 -> 2]
__global__ void pool_head(const float* __restrict__ h, const int* __restrict__ batch,
                          const float* __restrict__ Wf, const float* __restrict__ bf,
                          float* __restrict__ out, int N) {
    const int g = blockIdx.x;
    const int f = threadIdx.x;  // 128 threads
    int lo = 0, hi = N;
    while (lo < hi) { int m = (lo + hi) >> 1; if (batch[m] < g) lo = m + 1; else hi = m; }
    int lo2 = lo, hi2 = N;
    while (lo2 < hi2) { int m = (lo2 + hi2) >> 1; if (batch[m] < g + 1) lo2 = m + 1; else hi2 = m; }
    float s = 0.f;
    for (int n = lo; n < lo2; ++n) s += h[(size_t)n * F + f];
    const float cnt = (float)(lo2 - lo);
    const float rep = s / fmaxf(cnt, 1.0f);
    float p0 = rep * Wf[f * 2 + 0];
    float p1 = rep * Wf[f * 2 + 1];
    for (int o = 32; o; o >>= 1) { p0 += __shfl_xor(p0, o); p1 += __shfl_xor(p1, o); }
    __shared__ float r0[2], r1[2];
    if ((threadIdx.x & 63) == 0) { r0[threadIdx.x >> 6] = p0; r1[threadIdx.x >> 6] = p1; }
    __syncthreads();
    if (threadIdx.x == 0) out[g * 2 + 0] = r0[0] + r0[1] + bf[0];
    if (threadIdx.x == 1) out[g * 2 + 1] = r1[0] + r1[1] + bf[1];
}

extern "C" void kernel_launch(void* const* d_in, const int* in_sizes, int n_in,
                              void* d_out, int out_size, void* d_ws, size_t ws_size,
                              hipStream_t stream) {
    const float* x       = (const float*)d_in[0];
    const float* W1      = (const float*)d_in[1];
    const float* att_src = (const float*)d_in[2];
    const float* att_dst = (const float*)d_in[3];
    const float* b1      = (const float*)d_in[4];
    const float* W2      = (const float*)d_in[5];
    const float* b2      = (const float*)d_in[6];
    const float* Wf      = (const float*)d_in[7];
    const float* bf      = (const float*)d_in[8];
    const int*   ei      = (const int*)d_in[9];
    const int*   batch   = (const int*)d_in[10];
    float* out = (float*)d_out;

    // workspace layout: 3*6.4M floats + ~1.05M small = ~81 MB
    float* ws        = (float*)d_ws;
    float* h1        = ws;                       // [NN*F] gemm1 out; later final GCN out (alias)
    float* hg        = h1 + (size_t)NN * F;      // [NN*F] GAT output (relu'd)
    float* h2        = hg + (size_t)NN * F;      // [NN*F] gemm2 out
    float* asrc      = h2 + (size_t)NN * F;      // [NN]
    float* adst      = asrc + NN;                // [NN]
    float* dinv      = adst + NN;                // [NN]
    int*   deg       = (int*)(dinv + NN);        // [NN] histogram, then reused as scatter cursor
    int*   row_start = deg + NN;                 // [NN+1]
    int*   csr_src   = row_start + NN + 1;       // [EP]

    // CSR build (independent of feature path)
    hipMemsetAsync(deg, 0, NN * sizeof(int), stream);
    hist_deg<<<(EP + 255) / 256, 256, 0, stream>>>(ei, deg);
    scan_rows<<<1, 1024, 0, stream>>>(deg, row_start);
    hipMemsetAsync(deg, 0, NN * sizeof(int), stream);  // reuse as cursor
    scatter_csr<<<(EP + 255) / 256, 256, 0, stream>>>(ei, row_start, deg, csr_src);

    gemm128<<<NN / 2, 256, 0, stream>>>(x, W1, h1, NN);
    node_scores<<<(NN + 3) / 4, 256, 0, stream>>>(h1, att_src, att_dst, asrc, adst, NN);
    gat_gather<<<(NN + 3) / 4, 256, 0, stream>>>(row_start, csr_src, asrc, adst, h1, b1, hg);
    gemm128<<<NN / 2, 256, 0, stream>>>(hg, W2, h2, NN);
    make_dinv<<<(NN + 255) / 256, 256, 0, stream>>>(row_start, dinv);
    gcn_gather<<<(NN + 3) / 4, 256, 0, stream>>>(row_start, csr_src, dinv, h2, b2, h1);
    pool_head<<<NG, 128, 0, stream>>>(h1, batch, Wf, bf, out, NN);
}